// Round 9
// baseline (912.457 us; speedup 1.0000x reference)
//
#include <hip/hip_runtime.h>

// 3x3 stride-1 VALID conv, NCHW fp32 in/out, bf16 MFMA implicit GEMM.
// N=16, Cin=Cout=32, 512x512 -> 510x510.
// R9 = R8 (page-friendly PT=256, row-reuse, b128 LDS ops, 1-barrier/row)
// plus two changes:
//  - DOUBLE-BUFFERED LOAD BATCHES: issue row ir+4 at iter ir, commit row
//    ir+3 from the batch issued at iter ir-1. Commit's waitcnt retires
//    only the OLDER batch (separate register arrays -> vmcnt(9), never 0),
//    so ~18 loads/thread stay in flight continuously instead of draining
//    every row (fixes the ~60% DRAM duty cycle of R8's same-iter
//    issue->commit window).
//  - RT=10 (510=51x10): y-halo read overhead 1.33x -> 1.2x (-10% fetch),
//    51 prologues instead of 85.
// LDS ring unchanged (SLOTS=3, commit slot = ir%3, published 2 barriers
// before its read at iter ir+3). ~115 VGPR at __launch_bounds__(1024,4):
// spill-free (R3 lesson: spills show as +100s MB of scratch traffic).

namespace {
constexpr int NI    = 16;
constexpr int C_IN  = 32;
constexpr int HI    = 512;
constexpr int WI    = 512;
constexpr int C_OUT = 32;
constexpr int HO    = 510;
constexpr int WO    = 510;

constexpr int RT    = 10;         // output rows per block (510/10 = 51 exact)
constexpr int PT    = 256;        // output x-pixels per block
constexpr int XCOLS = 264;        // staged px per row: 256 core + 8 halo
constexpr int PSTR  = 40;         // shorts per pixel (80B stride, 16B aligned)
constexpr int SLOTS = 3;          // LDS row ring
constexpr int SLOTW = XCOLS * PSTR;   // 10560 shorts per row slot
constexpr int HIWI  = HI * WI;
constexpr int NT    = 1024;
}

typedef __attribute__((ext_vector_type(4))) float  floatx4;
typedef __attribute__((ext_vector_type(8))) __bf16 bf16x8;
typedef __attribute__((ext_vector_type(8))) unsigned short ushortx8;

// ---- weight prep: w [co][ci][3][3] f32 -> ws bf16 A-fragments [tap][h][lane][j]
// lane = quad*16 + l16; element j: co = h*16 + l16, ci = quad*8 + j.
__global__ void conv_wprep(const float* __restrict__ w, __bf16* __restrict__ ws) {
  const int t = threadIdx.x;
  for (int i = t; i < 9 * 2 * 64 * 8; i += 256) {
    const int j    = i & 7;
    const int lane = (i >> 3) & 63;
    const int h    = (i >> 9) & 1;
    const int tap  = i >> 10;
    const int co   = h * 16 + (lane & 15);
    const int ci   = (lane >> 4) * 8 + j;
    ws[i] = (__bf16)w[(co * C_IN + ci) * 9 + tap];
  }
}

__global__ __launch_bounds__(NT, 4)
void conv3x3_mfma(const float* __restrict__ x, const __bf16* __restrict__ ws,
                  const float* __restrict__ bias, float* __restrict__ out) {
  __shared__ __bf16 lds[SLOTS * SLOTW];   // 63360 B static

  const int t    = threadIdx.x;
  const int lane = t & 63;
  const int wv   = t >> 6;        // 0..15
  const int quad = lane >> 4;
  const int l16  = lane & 15;
  const int ch   = wv >> 3;       // co-half: channels [ch*16, ch*16+16)
  const int w8   = wv & 7;        // px window [w8*32, w8*32+32)

  const int x0 = blockIdx.x * PT;
  const int y0 = blockIdx.y * RT;
  const int n  = blockIdx.z;

  const float* xn = x + (size_t)n * C_IN * HIWI;

  // ---- staging geometry: thread t covers core px = t&255, ci octet cq = t>>8,
  // k=0..7 -> ci = cq*8+k. Per (cq,k) instruction-group: 256 consecutive px
  // = 1KB contiguous per plane (page-amortized). Commit packs 8 bf16 ->
  // single ds_write_b128 at 80B lane stride (2-way banks, free class).
  const int ps   = t & 255;
  const int cq   = t >> 8;                      // 0..3
  const int gofs = (cq * 8) * HIWI + x0 + ps;   // + k*HIWI + (y0+gr)*WI
  const int lofs = ps * PSTR + cq * 8;          // + slot*SLOTW

  // halo px 256..263 (x0=0: real; x0=256: clamped, feeds only invalid outputs)
  const bool hw  = (wv < 4);
  const int hci  = t >> 3;                      // 0..31 for t<256
  const int hpx  = 256 + (t & 7);
  int hgx = x0 + hpx; if (hgx > WI - 1) hgx = WI - 1;
  const int hgo  = hci * HIWI + hgx;
  const int hlo  = hpx * PSTR + hci;

  auto issue = [&](int gr, float (&b)[8], float& h) {   // 8(+1) loads, in flight
    const float* rb = xn + (size_t)(y0 + gr) * WI;
#pragma unroll
    for (int k = 0; k < 8; ++k) b[k] = rb[gofs + k * HIWI];
    if (hw) h = rb[hgo];
  };
  auto commit = [&](int slot, float (&b)[8], float h) { // cvt + one b128 write
    __bf16* s = lds + slot * SLOTW;
    union { __bf16 bb[8]; ushortx8 u; } pk;
#pragma unroll
    for (int k = 0; k < 8; ++k) pk.bb[k] = (__bf16)b[k];
    *reinterpret_cast<ushortx8*>(s + lofs) = pk.u;      // (ps*80+cq*16)B: 16B aligned
    if (hw) s[hlo] = (__bf16)h;
  };

  // ---- prologue: rows 0..2 staged (24 loads overlap), then prime batch A
  {
    float p0[8], p1[8], p2[8];
    float h0 = 0.f, h1 = 0.f, h2 = 0.f;
    issue(0, p0, h0); issue(1, p1, h1); issue(2, p2, h2);
    commit(0, p0, h0); commit(1, p1, h1); commit(2, p2, h2);
  }

  float fb[2][8];                 // two load batches in flight (parity ir&1)
  float fh[2] = {0.f, 0.f};
  issue(3, fb[1], fh[1]);         // row 3 -> committed at iter 0

  // ---- A fragments: 9 coalesced 16B loads from prepped ws (L2-resident).
  bf16x8 afrag[9];
#pragma unroll
  for (int tap = 0; tap < 9; ++tap)
    afrag[tap] = *reinterpret_cast<const bf16x8*>(ws + ((tap * 2 + ch) * 64 + lane) * 8);

  float bv[4];
#pragma unroll
  for (int r = 0; r < 4; ++r)
    bv[r] = bias[ch * 16 + quad * 4 + r];

  __syncthreads();

  const int pxb = x0 + w8 * 32 + l16;   // fragment f covers px = pxb + f*16
  floatx4 acc[3][2];                    // rotating: output row o lives in acc[o%3]

#pragma unroll
  for (int ir = 0; ir < RT + 2; ++ir) {           // input rows y0+0 .. y0+11
    // issue row ir+4 into this iteration's parity batch; the OTHER batch
    // (row ir+3, issued last iter) stays in flight until commit below.
    if (ir + 4 <= RT + 1) issue(ir + 4, fb[ir & 1], fh[ir & 1]);

    if (ir < RT) {                                // output row ir starts here
#pragma unroll
      for (int f = 0; f < 2; ++f)
        acc[ir % 3][f] = floatx4{bv[0], bv[1], bv[2], bv[3]};
    }

    // read this input row's 6 B-fragments ONCE (single b128 each)
    bf16x8 bf[2][3];
    const __bf16* sl = lds + (ir % SLOTS) * SLOTW + (w8 * 32 + l16) * PSTR + quad * 8;
#pragma unroll
    for (int f = 0; f < 2; ++f)
#pragma unroll
      for (int kx = 0; kx < 3; ++kx)
        bf[f][kx] = *reinterpret_cast<const bf16x8*>(sl + (f * 16 + kx) * PSTR);

    // each fragment feeds up to 3 output rows (ky = ir - o)
#pragma unroll
    for (int ky = 0; ky < 3; ++ky) {
      const int o = ir - ky;
      if (o < 0 || o >= RT) continue;
#pragma unroll
      for (int kx = 0; kx < 3; ++kx)
#pragma unroll
        for (int f = 0; f < 2; ++f)
          acc[o % 3][f] = __builtin_amdgcn_mfma_f32_16x16x32_bf16(
              afrag[ky * 3 + kx], bf[f][kx], acc[o % 3][f], 0, 0, 0);
    }

    if (ir >= 2) {   // output row o = ir-2 complete; 1KB runs per co-plane
      const int o = ir - 2;
      float* op = out + ((size_t)(n * C_OUT + ch * 16 + quad * 4) * HO + (y0 + o)) * WO + pxb;
#pragma unroll
      for (int f = 0; f < 2; ++f) {
        if (pxb + f * 16 < WO) {
#pragma unroll
          for (int r = 0; r < 4; ++r)
            op[r * (HO * WO) + f * 16] = acc[o % 3][f][r];   // co = ch*16+quad*4+r
        }
      }
    }

    __syncthreads();                 // all waves done reading slot ir%3
    // commit row ir+3 (batch issued at iter ir-1; waitcnt retires only that
    // batch, the row-ir+4 loads remain outstanding) into slot (ir+3)%3 = ir%3;
    // published by the barriers of iters ir+1/ir+2 before its read at ir+3.
    if (ir + 3 <= RT + 1) commit(ir % SLOTS, fb[(ir + 1) & 1], fh[(ir + 1) & 1]);
  }
}

extern "C" void kernel_launch(void* const* d_in, const int* in_sizes, int n_in,
                              void* d_out, int out_size, void* d_ws, size_t ws_size,
                              hipStream_t stream) {
  const float* x    = (const float*)d_in[0];
  const float* w    = (const float*)d_in[1];
  const float* bias = (const float*)d_in[2];
  float* out        = (float*)d_out;
  __bf16* ws        = (__bf16*)d_ws;          // needs 18432 B

  conv_wprep<<<dim3(1), 256, 0, stream>>>(w, ws);

  dim3 grid(WI / PT, HO / RT, NI);  // 2 x 51 x 16 = 1632 blocks, 1024 threads
  conv3x3_mfma<<<grid, NT, 0, stream>>>(x, ws, bias, out);
}